// Round 7
// baseline (351.404 us; speedup 1.0000x reference)
//
#include <hip/hip_runtime.h>
#include <hip/hip_bf16.h>

#define L 1024
#define D 128
#define NB 32
#define BQ 16

typedef __attribute__((ext_vector_type(8))) short short8;
typedef __attribute__((ext_vector_type(4))) short short4v;
typedef __attribute__((ext_vector_type(4))) float f32x4;

__device__ __forceinline__ unsigned short f2bf(float f) {
    union { float f; unsigned int u; } x; x.f = f;
    unsigned int r = x.u + 0x7FFF + ((x.u >> 16) & 1);
    return (unsigned short)(r >> 16);
}
__device__ __forceinline__ float bf2f(unsigned short u) {
    union { unsigned int u; float f; } x; x.u = ((unsigned int)u) << 16;
    return x.f;
}
__device__ __forceinline__ unsigned short f2h(float f) {
    union { _Float16 h; unsigned short u; } x; x.h = (_Float16)f;
    return x.u;
}
__device__ __forceinline__ float h2f(unsigned short u) {
    union { _Float16 h; unsigned short u; } x; x.u = u;
    return (float)x.h;
}

// ---------------------------------------------------------------------------
// Prep kernel (one launch):
//   blocks [0, 2048):    K fp32 [B][L][D] -> Kb bf16 [B][L][D]  (coalesced)
//   blocks [2048, 6144): V fp32 [B][L][D] -> Vt bf16 [B][D][L]  (32x32 LDS transpose)
// ---------------------------------------------------------------------------
__global__ void prep_kernel(const float* __restrict__ K, const float* __restrict__ V,
                            unsigned short* __restrict__ Kb, unsigned short* __restrict__ Vt) {
    __shared__ unsigned short t[32][40];
    int id = blockIdx.x;
    int tid = threadIdx.x;
    if (id < 2048) {
        size_t base = (size_t)id * 2048 + (size_t)tid * 8;
        float4 a = *(const float4*)(K + base);
        float4 c = *(const float4*)(K + base + 4);
        short8 o;
        o[0] = (short)f2bf(a.x); o[1] = (short)f2bf(a.y);
        o[2] = (short)f2bf(a.z); o[3] = (short)f2bf(a.w);
        o[4] = (short)f2bf(c.x); o[5] = (short)f2bf(c.y);
        o[6] = (short)f2bf(c.z); o[7] = (short)f2bf(c.w);
        *(short8*)(Kb + base) = o;
        return;
    }
    id -= 2048;
    int b = id >> 7;
    int rest = id & 127;
    int kt = rest >> 2, dt = rest & 3;
    int k0 = kt * 32, d0 = dt * 32;

    int kl = tid >> 3, dl4 = (tid & 7) * 4;
    const float* src = V + (((size_t)b * L + (k0 + kl)) * D) + d0 + dl4;
    float4 v = *(const float4*)src;
    t[dl4 + 0][kl] = f2bf(v.x);
    t[dl4 + 1][kl] = f2bf(v.y);
    t[dl4 + 2][kl] = f2bf(v.z);
    t[dl4 + 3][kl] = f2bf(v.w);
    __syncthreads();

    int dl = tid >> 3, kl4 = (tid & 7) * 4;
    unsigned short* dst = Vt + (((size_t)b * D + (d0 + dl)) * L) + k0 + kl4;
    short4v o;
    o[0] = (short)t[dl][kl4 + 0];
    o[1] = (short)t[dl][kl4 + 1];
    o[2] = (short)t[dl][kl4 + 2];
    o[3] = (short)t[dl][kl4 + 3];
    *(short4v*)dst = o;
}

// ---------------------------------------------------------------------------
// Fused attention, round 7. Swapped QK^T (mfma(K,Q) -> S^T): each thread's
// P-values are row-local (q = lane&15, k = (wave+4i)*16 + lg*4 + r).
//
// Round-6 lesson: vmcnt is ORDERED (oldest-first). Interleaving the ~900cy
// HBM kg load with the ~250cy L2 Kb loads inside each Phase-B iteration made
// every MFMA's Kb-wait also wait for the older kg load -> 16 exposed HBM
// round-trips per wave. Fix: separate the streams.
//   Phase A (new): burst-load ALL 16 float4 of this thread's kg slice
//     (ping-pong bursts of 4, MLP 8, <=32 regs), convert to fp16, ds_write
//     into the SAME S16 slots this thread's t-values will occupy. No extra
//     LDS, no barrier (producer == consumer thread). 16 waves/CU x 8
//     in-flight x 1KB = plenty to run this phase HBM-paced (~25us device).
//   Phase B: only vmem stream is Kb (L2) -> clean pipelining. Reads kg back
//     via ds_read (lgkmcnt - decoupled from vmcnt), t = exp(S)*kg -> same
//     slot as bf16. z1 in regs.
//   Phase D: e = exp(-t/z1) in-place in S16. Pure LDS+VALU.
//   Phase E: unchanged (e @ V from Vt, scale by 1/z2).
// kg stored fp16 not bf16: kg in [0,1), fp16 rel err 2^-11 -> negligible on
// an exp argument of ~1e-3; keeps absmax at the current ~5e-4 level.
// Design-for-64-VGPR throughout (rounds 0-4: allocator pins ~64 and spills).
// ---------------------------------------------------------------------------
__global__ __launch_bounds__(256, 4)
void attn_kernel(const float* __restrict__ Q, const unsigned short* __restrict__ Kb,
                 const float* __restrict__ scale_p, const float* __restrict__ kg,
                 const unsigned short* __restrict__ Vt, float* __restrict__ out) {
    __shared__ unsigned short S16[BQ * 1032];   // 16 x (1024+8): kg(fp16) -> t -> e
    __shared__ float zp1[4][BQ];                // per-wave partial z1
    __shared__ float zp2[4][BQ];                // per-wave partial z2

    const int tid = threadIdx.x;
    const int b  = blockIdx.x >> 6;
    const int q0 = (blockIdx.x & 63) * BQ;
    const float nsc = -scale_p[0];

    const int wave = tid >> 6, lane = tid & 63;
    const int lr = lane & 15;
    const int lg = lane >> 4;

    // ---- Q fragments (B-operand of the swapped MFMA) ------------------------
    short8 aq[4];
#pragma unroll
    for (int kb = 0; kb < 4; kb++) {
        const float* qp = Q + (((size_t)b * L) + q0 + lr) * D + kb * 32 + lg * 8;
        float4 v0 = *(const float4*)qp;
        float4 v1 = *(const float4*)(qp + 4);
        short8 o;
        o[0] = (short)f2bf(v0.x * nsc); o[1] = (short)f2bf(v0.y * nsc);
        o[2] = (short)f2bf(v0.z * nsc); o[3] = (short)f2bf(v0.w * nsc);
        o[4] = (short)f2bf(v1.x * nsc); o[5] = (short)f2bf(v1.y * nsc);
        o[6] = (short)f2bf(v1.z * nsc); o[7] = (short)f2bf(v1.w * nsc);
        aq[kb] = o;
    }

    // ---- Phase A: kg -> fp16 -> own t-slots in S16 (burst, MLP 8) ----------
    // This thread's kg coords: row q0+lr, cols wave*16 + 64*i + lg*4 + r.
    const float* kgq = kg + (((size_t)b * L) + q0 + lr) * L + wave * 16 + lg * 4;
    unsigned short* tbase = &S16[lr * 1032 + wave * 16 + lg * 4];  // slot i at +64*i
    {
        f32x4 ga[4], gb[4];
#pragma unroll
        for (int j = 0; j < 4; j++)
            ga[j] = __builtin_nontemporal_load((const f32x4*)(kgq + 64 * j));
#pragma unroll
        for (int j = 0; j < 4; j++)
            gb[j] = __builtin_nontemporal_load((const f32x4*)(kgq + 64 * (4 + j)));
#pragma unroll
        for (int j = 0; j < 4; j++) {
            short4v h; h[0] = (short)f2h(ga[j][0]); h[1] = (short)f2h(ga[j][1]);
            h[2] = (short)f2h(ga[j][2]); h[3] = (short)f2h(ga[j][3]);
            *(short4v*)(tbase + 64 * j) = h;
        }
#pragma unroll
        for (int j = 0; j < 4; j++)
            ga[j] = __builtin_nontemporal_load((const f32x4*)(kgq + 64 * (8 + j)));
#pragma unroll
        for (int j = 0; j < 4; j++) {
            short4v h; h[0] = (short)f2h(gb[j][0]); h[1] = (short)f2h(gb[j][1]);
            h[2] = (short)f2h(gb[j][2]); h[3] = (short)f2h(gb[j][3]);
            *(short4v*)(tbase + 64 * (4 + j)) = h;
        }
#pragma unroll
        for (int j = 0; j < 4; j++)
            gb[j] = __builtin_nontemporal_load((const f32x4*)(kgq + 64 * (12 + j)));
#pragma unroll
        for (int j = 0; j < 4; j++) {
            short4v h; h[0] = (short)f2h(ga[j][0]); h[1] = (short)f2h(ga[j][1]);
            h[2] = (short)f2h(ga[j][2]); h[3] = (short)f2h(ga[j][3]);
            *(short4v*)(tbase + 64 * (8 + j)) = h;
        }
#pragma unroll
        for (int j = 0; j < 4; j++) {
            short4v h; h[0] = (short)f2h(gb[j][0]); h[1] = (short)f2h(gb[j][1]);
            h[2] = (short)f2h(gb[j][2]); h[3] = (short)f2h(gb[j][3]);
            *(short4v*)(tbase + 64 * (12 + j)) = h;
        }
    }

    // ---- Phase B: S^T = K @ Q^T; t = exp(S)*kg -> same slot; z1 in regs ----
    // Only vmem stream here is Kb (L2): clean pipelining, no slow-load mixing.
    float z1p = 0.f;
#pragma unroll
    for (int i = 0; i < 16; i++) {
        int ct = wave + i * 4;
        const unsigned short* kp = Kb + (((size_t)b * L) + ct * 16 + lr) * D + lg * 8;
        f32x4 acc = {0.f, 0.f, 0.f, 0.f};
#pragma unroll
        for (int kb = 0; kb < 4; kb++) {
            short8 kf = *(const short8*)(kp + kb * 32);
            acc = __builtin_amdgcn_mfma_f32_16x16x32_bf16(kf, aq[kb], acc, 0, 0, 0);
        }
        short4v gh = *(const short4v*)(tbase + 64 * i);   // kg fp16 (lgkmcnt)
        float p0 = __expf(acc[0]);              // no max pass: S ~ N(0,1)
        float p1 = __expf(acc[1]);
        float p2 = __expf(acc[2]);
        float p3 = __expf(acc[3]);
        z1p += (p0 + p1) + (p2 + p3);
        short4v o;
        o[0] = (short)f2bf(p0 * h2f((unsigned short)gh[0]));
        o[1] = (short)f2bf(p1 * h2f((unsigned short)gh[1]));
        o[2] = (short)f2bf(p2 * h2f((unsigned short)gh[2]));
        o[3] = (short)f2bf(p3 * h2f((unsigned short)gh[3]));
        *(short4v*)(tbase + 64 * i) = o;
    }
    // reduce z1 across the 4 lanes sharing this q-row (bits 4,5 of lane id)
    z1p += __shfl_xor(z1p, 16, 64);
    z1p += __shfl_xor(z1p, 32, 64);
    if (lg == 0) zp1[wave][lr] = z1p;
    __syncthreads();

    // ---- Phase D: e = exp(-t/z1); pure LDS+VALU, no global loads -----------
    const float iz1 = 1.0f / (zp1[0][lr] + zp1[1][lr] + zp1[2][lr] + zp1[3][lr]);
    float z2p = 0.f;
#pragma unroll
    for (int j = 0; j < 16; j++) {
        short4v* pp = (short4v*)(tbase + 64 * j);
        short4v v = *pp;
        float e0 = __expf(-bf2f((unsigned short)v[0]) * iz1);
        float e1 = __expf(-bf2f((unsigned short)v[1]) * iz1);
        float e2 = __expf(-bf2f((unsigned short)v[2]) * iz1);
        float e3 = __expf(-bf2f((unsigned short)v[3]) * iz1);
        z2p += (e0 + e1) + (e2 + e3);
        short4v o; o[0] = (short)f2bf(e0); o[1] = (short)f2bf(e1);
        o[2] = (short)f2bf(e2); o[3] = (short)f2bf(e3);
        *pp = o;
    }
    z2p += __shfl_xor(z2p, 16, 64);
    z2p += __shfl_xor(z2p, 32, 64);
    if (lg == 0) zp2[wave][lr] = z2p;
    __syncthreads();

    // ---- Phase E: out = (e @ V) * (1/z2) ------------------------------------
    const int dt0 = wave * 2;
    f32x4 acc0 = {0.f, 0.f, 0.f, 0.f}, acc1 = {0.f, 0.f, 0.f, 0.f};
    const unsigned short* vt0 = Vt + (((size_t)b * D) + dt0 * 16 + lr) * L + lg * 8;
    const unsigned short* vt1 = vt0 + (size_t)16 * L;
    const unsigned short* brow = &S16[lr * 1032 + lg * 8];
#pragma unroll 8
    for (int kb = 0; kb < 32; kb++) {
        short8 a  = *(const short8*)(brow + kb * 32);
        short8 b0 = *(const short8*)(vt0 + kb * 32);
        short8 b1 = *(const short8*)(vt1 + kb * 32);
        acc0 = __builtin_amdgcn_mfma_f32_16x16x32_bf16(a, b0, acc0, 0, 0, 0);
        acc1 = __builtin_amdgcn_mfma_f32_16x16x32_bf16(a, b1, acc1, 0, 0, 0);
    }
    float* orow = out + (((size_t)b * L) + q0) * D;
#pragma unroll
    for (int r = 0; r < 4; r++) {
        int rq = lg * 4 + r;
        float rs = 1.0f / (zp2[0][rq] + zp2[1][rq] + zp2[2][rq] + zp2[3][rq]);
        orow[(size_t)rq * D + dt0 * 16 + lr]       = acc0[r] * rs;
        orow[(size_t)rq * D + (dt0 + 1) * 16 + lr] = acc1[r] * rs;
    }
}

extern "C" void kernel_launch(void* const* d_in, const int* in_sizes, int n_in,
                              void* d_out, int out_size, void* d_ws, size_t ws_size,
                              hipStream_t stream) {
    const float* Q     = (const float*)d_in[0];
    const float* K     = (const float*)d_in[1];
    const float* V     = (const float*)d_in[2];
    const float* scale = (const float*)d_in[3];
    const float* kg    = (const float*)d_in[4];
    float* out = (float*)d_out;
    unsigned short* Vt = (unsigned short*)d_ws;                        // 8 MB
    unsigned short* Kb = (unsigned short*)d_ws + (size_t)NB * D * L;   // 8 MB

    prep_kernel<<<6144, 256, 0, stream>>>(K, V, Kb, Vt);
    attn_kernel<<<NB * (L / BQ), 256, 0, stream>>>(Q, Kb, scale, kg, Vt, out);
}

// Round 9
// 339.979 us; speedup vs baseline: 1.0336x; 1.0336x over previous
//
#include <hip/hip_runtime.h>
#include <hip/hip_bf16.h>

#define L 1024
#define D 128
#define NB 32
#define BQ 16

typedef __attribute__((ext_vector_type(8))) short short8;
typedef __attribute__((ext_vector_type(4))) short short4v;
typedef __attribute__((ext_vector_type(4))) float f32x4;

__device__ __forceinline__ unsigned short f2bf(float f) {
    union { float f; unsigned int u; } x; x.f = f;
    unsigned int r = x.u + 0x7FFF + ((x.u >> 16) & 1);
    return (unsigned short)(r >> 16);
}
__device__ __forceinline__ float bf2f(unsigned short u) {
    union { unsigned int u; float f; } x; x.u = ((unsigned int)u) << 16;
    return x.f;
}
__device__ __forceinline__ unsigned short f2h(float f) {
    union { _Float16 h; unsigned short u; } x; x.h = (_Float16)f;
    return x.u;
}
__device__ __forceinline__ float h2f(unsigned short u) {
    union { _Float16 h; unsigned short u; } x; x.u = u;
    return (float)x.h;
}

// ---------------------------------------------------------------------------
// Prep kernel (one launch):
//   blocks [0, 2048):    K fp32 [B][L][D] -> Kb bf16 [B][L][D]  (coalesced)
//   blocks [2048, 6144): V fp32 [B][L][D] -> Vt bf16 [B][D][L]  (32x32 LDS transpose)
// ---------------------------------------------------------------------------
__global__ void prep_kernel(const float* __restrict__ K, const float* __restrict__ V,
                            unsigned short* __restrict__ Kb, unsigned short* __restrict__ Vt) {
    __shared__ unsigned short t[32][40];
    int id = blockIdx.x;
    int tid = threadIdx.x;
    if (id < 2048) {
        size_t base = (size_t)id * 2048 + (size_t)tid * 8;
        float4 a = *(const float4*)(K + base);
        float4 c = *(const float4*)(K + base + 4);
        short8 o;
        o[0] = (short)f2bf(a.x); o[1] = (short)f2bf(a.y);
        o[2] = (short)f2bf(a.z); o[3] = (short)f2bf(a.w);
        o[4] = (short)f2bf(c.x); o[5] = (short)f2bf(c.y);
        o[6] = (short)f2bf(c.z); o[7] = (short)f2bf(c.w);
        *(short8*)(Kb + base) = o;
        return;
    }
    id -= 2048;
    int b = id >> 7;
    int rest = id & 127;
    int kt = rest >> 2, dt = rest & 3;
    int k0 = kt * 32, d0 = dt * 32;

    int kl = tid >> 3, dl4 = (tid & 7) * 4;
    const float* src = V + (((size_t)b * L + (k0 + kl)) * D) + d0 + dl4;
    float4 v = *(const float4*)src;
    t[dl4 + 0][kl] = f2bf(v.x);
    t[dl4 + 1][kl] = f2bf(v.y);
    t[dl4 + 2][kl] = f2bf(v.z);
    t[dl4 + 3][kl] = f2bf(v.w);
    __syncthreads();

    int dl = tid >> 3, kl4 = (tid & 7) * 4;
    unsigned short* dst = Vt + (((size_t)b * D + (d0 + dl)) * L) + k0 + kl4;
    short4v o;
    o[0] = (short)t[dl][kl4 + 0];
    o[1] = (short)t[dl][kl4 + 1];
    o[2] = (short)t[dl][kl4 + 2];
    o[3] = (short)t[dl][kl4 + 3];
    *(short4v*)dst = o;
}

// ---------------------------------------------------------------------------
// Fused attention, round 8 (resubmit; previous run died to a container
// failure, not the kernel). Swapped QK^T (mfma(K,Q) -> S^T): each thread's
// P-values are row-local (q = lane&15, k = (wave+4i)*16 + lg*4 + r).
//
// Stream separation (round-6 lesson: vmcnt is ordered, mixing the ~900cy
// HBM kg stream with ~250cy L2 Kb loads serializes Phase B), implemented
// within the allocator's HARD 64-VGPR ceiling (rounds 3/4/7: anything
// holding >4 float4 loads + aq live spills 40+ MB to scratch):
//   Phase A: kg -> fp16 -> this thread's own S16 slots, in 4 sequential
//     bursts of 4 nontemporal float4 loads. 4 outstanding x 16 waves/CU
//     = 64 KB/CU in flight >> the ~22 KB needed to run HBM-paced; load
//     values die into ds_writes within each burst (peak live ~48 regs).
//   Phase B: only vmem stream is Kb (L2) -> clean pipelining. kg comes
//     back via ds_read (lgkmcnt, decoupled from vmcnt).
//     t = exp(S)*kg -> same slot (bf16). z1 in regs (2 shuffles).
//   Phase D: e = exp(-t/z1) in-place in S16. Pure LDS+VALU.
//   Phase E: unchanged (e @ V from Vt, scale by 1/z2).
// ---------------------------------------------------------------------------
__global__ __launch_bounds__(256, 4)
void attn_kernel(const float* __restrict__ Q, const unsigned short* __restrict__ Kb,
                 const float* __restrict__ scale_p, const float* __restrict__ kg,
                 const unsigned short* __restrict__ Vt, float* __restrict__ out) {
    __shared__ unsigned short S16[BQ * 1032];   // 16 x (1024+8): kg(fp16) -> t -> e
    __shared__ float zp1[4][BQ];                // per-wave partial z1
    __shared__ float zp2[4][BQ];                // per-wave partial z2

    const int tid = threadIdx.x;
    const int b  = blockIdx.x >> 6;
    const int q0 = (blockIdx.x & 63) * BQ;
    const float nsc = -scale_p[0];

    const int wave = tid >> 6, lane = tid & 63;
    const int lr = lane & 15;
    const int lg = lane >> 4;

    // ---- Q fragments (B-operand of the swapped MFMA) ------------------------
    short8 aq[4];
#pragma unroll
    for (int kb = 0; kb < 4; kb++) {
        const float* qp = Q + (((size_t)b * L) + q0 + lr) * D + kb * 32 + lg * 8;
        float4 v0 = *(const float4*)qp;
        float4 v1 = *(const float4*)(qp + 4);
        short8 o;
        o[0] = (short)f2bf(v0.x * nsc); o[1] = (short)f2bf(v0.y * nsc);
        o[2] = (short)f2bf(v0.z * nsc); o[3] = (short)f2bf(v0.w * nsc);
        o[4] = (short)f2bf(v1.x * nsc); o[5] = (short)f2bf(v1.y * nsc);
        o[6] = (short)f2bf(v1.z * nsc); o[7] = (short)f2bf(v1.w * nsc);
        aq[kb] = o;
    }

    // ---- Phase A: kg -> fp16 -> own t-slots in S16; bursts of 4 (16 regs) --
    // This thread's kg coords: row q0+lr, cols wave*16 + 64*i + lg*4 + r.
    const float* kgq = kg + (((size_t)b * L) + q0 + lr) * L + wave * 16 + lg * 4;
    unsigned short* tbase = &S16[lr * 1032 + wave * 16 + lg * 4];  // slot i at +64*i
#pragma unroll
    for (int io = 0; io < 4; io++) {
        f32x4 g[4];
#pragma unroll
        for (int j = 0; j < 4; j++)
            g[j] = __builtin_nontemporal_load((const f32x4*)(kgq + 64 * (io * 4 + j)));
#pragma unroll
        for (int j = 0; j < 4; j++) {
            short4v h;
            h[0] = (short)f2h(g[j][0]); h[1] = (short)f2h(g[j][1]);
            h[2] = (short)f2h(g[j][2]); h[3] = (short)f2h(g[j][3]);
            *(short4v*)(tbase + 64 * (io * 4 + j)) = h;
        }
    }
    __builtin_amdgcn_sched_barrier(0);          // fence A|B: keep streams apart

    // ---- Phase B: S^T = K @ Q^T; t = exp(S)*kg -> same slot; z1 in regs ----
    // Only vmem stream here is Kb (L2): clean pipelining, no slow-load mixing.
    float z1p = 0.f;
#pragma unroll
    for (int i = 0; i < 16; i++) {
        int ct = wave + i * 4;
        const unsigned short* kp = Kb + (((size_t)b * L) + ct * 16 + lr) * D + lg * 8;
        f32x4 acc = {0.f, 0.f, 0.f, 0.f};
#pragma unroll
        for (int kb = 0; kb < 4; kb++) {
            short8 kf = *(const short8*)(kp + kb * 32);
            acc = __builtin_amdgcn_mfma_f32_16x16x32_bf16(kf, aq[kb], acc, 0, 0, 0);
        }
        short4v gh = *(const short4v*)(tbase + 64 * i);   // kg fp16 (lgkmcnt)
        float p0 = __expf(acc[0]);              // no max pass: S ~ N(0,1)
        float p1 = __expf(acc[1]);
        float p2 = __expf(acc[2]);
        float p3 = __expf(acc[3]);
        z1p += (p0 + p1) + (p2 + p3);
        short4v o;
        o[0] = (short)f2bf(p0 * h2f((unsigned short)gh[0]));
        o[1] = (short)f2bf(p1 * h2f((unsigned short)gh[1]));
        o[2] = (short)f2bf(p2 * h2f((unsigned short)gh[2]));
        o[3] = (short)f2bf(p3 * h2f((unsigned short)gh[3]));
        *(short4v*)(tbase + 64 * i) = o;
    }
    // reduce z1 across the 4 lanes sharing this q-row (bits 4,5 of lane id)
    z1p += __shfl_xor(z1p, 16, 64);
    z1p += __shfl_xor(z1p, 32, 64);
    if (lg == 0) zp1[wave][lr] = z1p;
    __syncthreads();

    // ---- Phase D: e = exp(-t/z1); pure LDS+VALU, no global loads -----------
    const float iz1 = 1.0f / (zp1[0][lr] + zp1[1][lr] + zp1[2][lr] + zp1[3][lr]);
    float z2p = 0.f;
#pragma unroll
    for (int j = 0; j < 16; j++) {
        short4v* pp = (short4v*)(tbase + 64 * j);
        short4v v = *pp;
        float e0 = __expf(-bf2f((unsigned short)v[0]) * iz1);
        float e1 = __expf(-bf2f((unsigned short)v[1]) * iz1);
        float e2 = __expf(-bf2f((unsigned short)v[2]) * iz1);
        float e3 = __expf(-bf2f((unsigned short)v[3]) * iz1);
        z2p += (e0 + e1) + (e2 + e3);
        short4v o; o[0] = (short)f2bf(e0); o[1] = (short)f2bf(e1);
        o[2] = (short)f2bf(e2); o[3] = (short)f2bf(e3);
        *pp = o;
    }
    z2p += __shfl_xor(z2p, 16, 64);
    z2p += __shfl_xor(z2p, 32, 64);
    if (lg == 0) zp2[wave][lr] = z2p;
    __syncthreads();

    // ---- Phase E: out = (e @ V) * (1/z2) ------------------------------------
    const int dt0 = wave * 2;
    f32x4 acc0 = {0.f, 0.f, 0.f, 0.f}, acc1 = {0.f, 0.f, 0.f, 0.f};
    const unsigned short* vt0 = Vt + (((size_t)b * D) + dt0 * 16 + lr) * L + lg * 8;
    const unsigned short* vt1 = vt0 + (size_t)16 * L;
    const unsigned short* brow = &S16[lr * 1032 + lg * 8];
#pragma unroll 8
    for (int kb = 0; kb < 32; kb++) {
        short8 a  = *(const short8*)(brow + kb * 32);
        short8 b0 = *(const short8*)(vt0 + kb * 32);
        short8 b1 = *(const short8*)(vt1 + kb * 32);
        acc0 = __builtin_amdgcn_mfma_f32_16x16x32_bf16(a, b0, acc0, 0, 0, 0);
        acc1 = __builtin_amdgcn_mfma_f32_16x16x32_bf16(a, b1, acc1, 0, 0, 0);
    }
    float* orow = out + (((size_t)b * L) + q0) * D;
#pragma unroll
    for (int r = 0; r < 4; r++) {
        int rq = lg * 4 + r;
        float rs = 1.0f / (zp2[0][rq] + zp2[1][rq] + zp2[2][rq] + zp2[3][rq]);
        orow[(size_t)rq * D + dt0 * 16 + lr]       = acc0[r] * rs;
        orow[(size_t)rq * D + (dt0 + 1) * 16 + lr] = acc1[r] * rs;
    }
}

extern "C" void kernel_launch(void* const* d_in, const int* in_sizes, int n_in,
                              void* d_out, int out_size, void* d_ws, size_t ws_size,
                              hipStream_t stream) {
    const float* Q     = (const float*)d_in[0];
    const float* K     = (const float*)d_in[1];
    const float* V     = (const float*)d_in[2];
    const float* scale = (const float*)d_in[3];
    const float* kg    = (const float*)d_in[4];
    float* out = (float*)d_out;
    unsigned short* Vt = (unsigned short*)d_ws;                        // 8 MB
    unsigned short* Kb = (unsigned short*)d_ws + (size_t)NB * D * L;   // 8 MB

    prep_kernel<<<6144, 256, 0, stream>>>(K, V, Kb, Vt);
    attn_kernel<<<NB * (L / BQ), 256, 0, stream>>>(Q, Kb, scale, kg, Vt, out);
}